// Round 12
// baseline (160.065 us; speedup 1.0000x reference)
//
#include <hip/hip_runtime.h>
#include <cstddef>

// Problem constants
#define NB   4
#define CIN  256
#define TT   16
#define HH   28
#define WW   28
#define LL   12544           // 16*28*28 = 784*16
#define MIDC 32
#define KCC  128
#define VCC  256
#define HC   8
#define HK   16
#define HV   32
#define CTXSPLIT 14          // 392 chunks = 14 splits * 4 waves * 7 chunks
#define CTXSTR 544
#define EPSV 1e-5f

typedef __attribute__((ext_vector_type(8))) short bf16x8;
typedef __attribute__((ext_vector_type(8))) unsigned short u16x8;
typedef __attribute__((ext_vector_type(4))) float f32x4;
typedef __attribute__((ext_vector_type(4))) unsigned short u16x4;

__device__ __forceinline__ float b2f(unsigned short u) {
    return __builtin_bit_cast(float, ((unsigned int)u) << 16);
}
__device__ __forceinline__ unsigned short f2b(float f) {
    unsigned int u = __builtin_bit_cast(unsigned int, f);
    u += 0x7FFFu + ((u >> 16) & 1u);          // RNE
    return (unsigned short)(u >> 16);
}

// sizes (elements)
#define XTF_N_STRIDE 3211264ull        // 784*8*512 shorts per sample (xtf/aggf)
#define MID_SET_STRIDE 1605632ull      // NB*32*12544 elems per set

struct WconvA { const float* w1[4]; const float* w2[4]; };
struct Pw1M  { const short* wt[3]; const float* b[3]; unsigned short* out[3]; };
struct DwA   { const unsigned short* in[3]; const float* w[3]; const float* b[3]; unsigned short* out[3]; };
struct Pw2M  { const short* w2f; const unsigned short* d; const float* b[3]; unsigned short* out[3]; };

// ---- weights -> fragment-major bf16 tables --------------------------------
__global__ __launch_bounds__(256) void wconv_kernel(WconvA a, short* __restrict__ w1f,
                                                    short* __restrict__ w2f)
{
    const int g = blockIdx.x*256 + threadIdx.x;
    if (g < 4096) {
        const int L = g & 63, kap = (g >> 6) & 7, mt = (g >> 9) & 1, set = g >> 10;
        const int m = 16*mt + (L & 15);
        const int c0 = 32*kap + 8*(L >> 4);
        const float* wp = a.w1[set] + m*CIN + c0;
#pragma unroll
        for (int j = 0; j < 8; ++j) w1f[(size_t)g*8 + j] = (short)f2b(wp[j]);
    } else if (g < 4096 + 3072) {
        const int g2 = g - 4096;
        const int L = g2 & 63, mtg = g2 >> 6;
        int set, mtl;
        if (mtg < 8)       { set = 0; mtl = mtg; }
        else if (mtg < 16) { set = 1; mtl = mtg - 8; }
        else if (mtg < 32) { set = 2; mtl = mtg - 16; }
        else               { set = 3; mtl = mtg - 32; }
        const int m = 16*mtl + (L & 15);
        const int c0 = 8*(L >> 4);
        const float* wp = a.w2[set] + m*MIDC + c0;
#pragma unroll
        for (int j = 0; j < 8; ++j) w2f[(size_t)g2*8 + j] = (short)f2b(wp[j]);
    }
}

// ---- input fp32 [N][256][L] -> xtf bf16 frag-major (high-TLP gather) --------
__global__ __launch_bounds__(256) void transp_in(const float* __restrict__ in,
                                                 short* __restrict__ xtf)
{
    const int n = blockIdx.y;
    const int tau = blockIdx.x >> 1;
    const int idx = (blockIdx.x & 1)*256 + threadIdx.x;    // 0..511
    const int kap = idx >> 6, L = idx & 63;
    const int l = 16*tau + (L & 15);
    const int c0 = 32*kap + 8*(L >> 4);
    const float* ip = in + ((size_t)n*CIN + c0)*LL + l;
    bf16x8 vv;
#pragma unroll
    for (int j = 0; j < 8; ++j) vv[j] = (short)f2b(ip[(size_t)j*LL]);
    *reinterpret_cast<bf16x8*>(xtf + (size_t)n*XTF_N_STRIDE +
                               ((size_t)(tau*8 + kap)*512 + L*8)) = vv;
}

// ---- pw1 MFMA (NS sets share B-frags): [32x256]@[256xL] + b -> mid bf16 ----
// B read linearly from frag-major xtf/aggf (bf16x8 per lane).
template<int NS>
__global__ __launch_bounds__(256) void pw1_frag_t(const short* __restrict__ xtf, Pw1M a)
{
    const int n = blockIdx.y, bx = blockIdx.x;
    const int t = threadIdx.x, wid = t >> 6, lane = t & 63;
    const int mt = wid & 1, lh = wid >> 1;
    const int tau0 = bx*8 + lh*4;
    const short* xb = xtf + (size_t)n*XTF_N_STRIDE;

    f32x4 acc[NS][4];
#pragma unroll
    for (int s = 0; s < NS; ++s)
#pragma unroll
        for (int i = 0; i < 4; ++i)
#pragma unroll
            for (int r = 0; r < 4; ++r) acc[s][i][r] = 0.f;

    for (int kap = 0; kap < 8; ++kap) {
        bf16x8 bfr[4];
#pragma unroll
        for (int i = 0; i < 4; ++i)
            bfr[i] = *reinterpret_cast<const bf16x8*>(
                xb + ((size_t)((tau0 + i)*8 + kap)*512 + lane*8));
#pragma unroll
        for (int s = 0; s < NS; ++s) {
            bf16x8 afr = *reinterpret_cast<const bf16x8*>(
                a.wt[s] + ((mt*8 + kap)*512 + lane*8));
#pragma unroll
            for (int i = 0; i < 4; ++i)
                acc[s][i] = __builtin_amdgcn_mfma_f32_16x16x32_bf16(afr, bfr[i], acc[s][i], 0, 0, 0);
        }
    }
    const int col = lane & 15;
    const int m0 = mt*16 + (lane >> 4)*4;
#pragma unroll
    for (int s = 0; s < NS; ++s) {
        const float* bb = a.b[s];
        unsigned short* op = a.out[s] + (size_t)n*MIDC*LL;
#pragma unroll
        for (int r = 0; r < 4; ++r) {
            const float bv = bb[m0 + r];
#pragma unroll
            for (int i = 0; i < 4; ++i)
                op[(size_t)(m0 + r)*LL + (tau0 + i)*16 + col] = f2b(acc[s][i][r] + bv);
        }
    }
}

// ---- depthwise 3x3x3, pad 1: register sliding window over t ----------------
struct Row6 { float v[6]; };

__device__ __forceinline__ Row6 load_row(const unsigned short* base, int zz, int yy, int x0)
{
    Row6 r;
    const bool ok = (zz >= 0) && (zz < TT) && (yy >= 0) && (yy < HH);
    if (ok) {
        const unsigned short* p = base + zz*(HH*WW) + yy*WW + x0;
        u16x4 m4 = *reinterpret_cast<const u16x4*>(p);
        r.v[0] = (x0 > 0)  ? b2f(p[-1]) : 0.f;
        r.v[1] = b2f(m4[0]); r.v[2] = b2f(m4[1]);
        r.v[3] = b2f(m4[2]); r.v[4] = b2f(m4[3]);
        r.v[5] = (x0 < 24) ? b2f(p[4]) : 0.f;
    } else {
#pragma unroll
        for (int i = 0; i < 6; ++i) r.v[i] = 0.f;
    }
    return r;
}

__device__ __forceinline__ void acc9(float& a0, float& a1, float& a2, float& a3,
                                     const Row6* rows, const float* w9)
{
#pragma unroll
    for (int dy = 0; dy < 3; ++dy)
#pragma unroll
        for (int dx = 0; dx < 3; ++dx) {
            const float wv = w9[dy*3 + dx];
            a0 = fmaf(wv, rows[dy].v[0 + dx], a0);
            a1 = fmaf(wv, rows[dy].v[1 + dx], a1);
            a2 = fmaf(wv, rows[dy].v[2 + dx], a2);
            a3 = fmaf(wv, rows[dy].v[3 + dx], a3);
        }
}

__global__ __launch_bounds__(256) void dw_reg(DwA a)
{
    const int tid = threadIdx.x;
    if (tid >= 196) return;                  // 7 x-groups * 28 y
    const int z  = blockIdx.z;
    const int nm = blockIdx.y;               // n*32 + m
    const int m  = nm & (MIDC-1);
    const int t0 = blockIdx.x * 8;           // t-half

    const float* wp = a.w[z] + m*27;
    float wv[27];
#pragma unroll
    for (int i = 0; i < 27; ++i) wv[i] = wp[i];
    const float bias = a.b[z][m];

    const int xg = tid % 7, y = tid / 7;
    const int x0 = xg*4;
    const unsigned short* ip = a.in[z] + (size_t)nm*LL;
    unsigned short* op = a.out[z] + (size_t)nm*LL;

    Row6 win[3][3];
#pragma unroll
    for (int dy = 0; dy < 3; ++dy) {
        win[0][dy] = load_row(ip, t0-1, y+dy-1, x0);
        win[1][dy] = load_row(ip, t0,   y+dy-1, x0);
    }
#pragma unroll
    for (int tt = 0; tt < 8; ++tt) {
        const int p0 = tt % 3, p1 = (tt+1) % 3, p2 = (tt+2) % 3;
        const int znew = t0 + tt + 1;
        win[p2][0] = load_row(ip, znew, y-1, x0);
        win[p2][1] = load_row(ip, znew, y,   x0);
        win[p2][2] = load_row(ip, znew, y+1, x0);

        float a0 = bias, a1 = bias, a2 = bias, a3 = bias;
        acc9(a0, a1, a2, a3, win[p0], wv);
        acc9(a0, a1, a2, a3, win[p1], wv + 9);
        acc9(a0, a1, a2, a3, win[p2], wv + 18);

        u16x4 o4 = { f2b(a0), f2b(a1), f2b(a2), f2b(a3) };
        *reinterpret_cast<u16x4*>(op + (size_t)(t0+tt)*(HH*WW) + y*WW + x0) = o4;
    }
}

// ---- pw2 MFMA (gathers B from d directly): [OCx32]@[32xL]+b -> K/Q/V bf16 --
__global__ __launch_bounds__(256) void pw2_g(Pw2M a)
{
    const int z = blockIdx.z, n = blockIdx.y, bx = blockIdx.x;
    int set, chunk;
    if (z < 2)      { set = 0; chunk = z; }
    else if (z < 4) { set = 1; chunk = z - 2; }
    else            { set = 2; chunk = z - 4; }
    const int OC   = (set == 2) ? 256 : 128;
    const int off2 = (set == 0) ? 0 : (set == 1) ? 8 : 16;

    const int t = threadIdx.x, wid = t >> 6, lane = t & 63;
    const int mtile = chunk*4 + wid;
    bf16x8 afr = *reinterpret_cast<const bf16x8*>(
        a.w2f + ((size_t)(off2 + mtile)*512 + lane*8));
    const unsigned short* db = a.d + (size_t)set*MID_SET_STRIDE + (size_t)n*MIDC*LL;
    const int colb = lane & 15, c0 = 8*(lane >> 4);

    f32x4 acc[4];
#pragma unroll
    for (int i = 0; i < 4; ++i) {
#pragma unroll
        for (int r = 0; r < 4; ++r) acc[i][r] = 0.f;
        const unsigned short* p = db + (size_t)c0*LL + (bx*4 + i)*16 + colb;
        bf16x8 bfr;
#pragma unroll
        for (int j = 0; j < 8; ++j) bfr[j] = (short)p[(size_t)j*LL];
        acc[i] = __builtin_amdgcn_mfma_f32_16x16x32_bf16(afr, bfr, acc[i], 0, 0, 0);
    }
    const float* bb = a.b[set];
    unsigned short* op = a.out[set] + (size_t)n*OC*LL;
    const int m0 = 16*mtile + (lane >> 4)*4;
#pragma unroll
    for (int r = 0; r < 4; ++r) {
        const float bv = bb[m0 + r];
#pragma unroll
        for (int i = 0; i < 4; ++i)
            op[(size_t)(m0 + r)*LL + (bx*4 + i)*16 + colb] = f2b(acc[i][r] + bv);
    }
}

// ---- context via MFMA: ctx_partial[k][v] = sum_l exp(K[k,l]) V[v,l] ---------
__global__ __launch_bounds__(256) void ctx_mfma(
    const unsigned short* __restrict__ Kb, const unsigned short* __restrict__ Vb,
    float* __restrict__ ctxp)
{
    const int nh = blockIdx.y;               // 32
    const int sp = blockIdx.x;               // 14
    const int n = nh >> 3, h = nh & 7;
    const int t = threadIdx.x, w = t >> 6, lane = t & 63;
    const int i = lane & 15, q = lane >> 4;

    const unsigned short* Kp = Kb + ((size_t)(n*KCC + h*HK))*LL;
    const unsigned short* Vp = Vb + ((size_t)(n*VCC + h*HV))*LL;

    f32x4 a0 = {0.f,0.f,0.f,0.f}, a1 = {0.f,0.f,0.f,0.f};
    float asum = 0.f;

    const int cbase = sp*28 + w*7;           // 7 chunks of 32 l per wave
#pragma unroll 2
    for (int cc = 0; cc < 7; ++cc) {
        const int l0 = (cbase + cc)*32 + 8*q;
        bf16x8 kf = *reinterpret_cast<const bf16x8*>(Kp + (size_t)i*LL + l0);
        bf16x8 pf;
#pragma unroll
        for (int j = 0; j < 8; ++j) {
            const float e = __expf(b2f((unsigned short)kf[j]));
            asum += e;
            pf[j] = (short)f2b(e);
        }
        bf16x8 b0 = *reinterpret_cast<const bf16x8*>(Vp + (size_t)i*LL + l0);
        bf16x8 b1 = *reinterpret_cast<const bf16x8*>(Vp + (size_t)(i+16)*LL + l0);
        a0 = __builtin_amdgcn_mfma_f32_16x16x32_bf16(pf, b0, a0, 0, 0, 0);
        a1 = __builtin_amdgcn_mfma_f32_16x16x32_bf16(pf, b1, a1, 0, 0, 0);
    }
    asum += __shfl_xor(asum, 16);
    asum += __shfl_xor(asum, 32);

    __shared__ float cs[4][512];
    __shared__ float as[4][16];
#pragma unroll
    for (int r = 0; r < 4; ++r) {
        cs[w][(q*4 + r)*32 + i]      = a0[r];
        cs[w][(q*4 + r)*32 + 16 + i] = a1[r];
    }
    if (q == 0) as[w][i] = asum;
    __syncthreads();
    float* cp = ctxp + ((size_t)nh*CTXSPLIT + sp)*CTXSTR;
    for (int p = t; p < 512; p += 256)
        cp[p] = cs[0][p] + cs[1][p] + cs[2][p] + cs[3][p];
    if (t < 16) cp[512 + t] = as[0][t] + as[1][t] + as[2][t] + as[3][t];
}

__global__ void ctx_reduce(const float* __restrict__ ctxp, float* __restrict__ ctx)
{
    const int idx = blockIdx.x*256 + threadIdx.x;   // 16384
    const int nh = idx >> 9;
    const int p  = idx & 511;
    const int k  = p >> 5;
    float s = 0.f, se = 0.f;
    for (int sp = 0; sp < CTXSPLIT; ++sp) {
        const float* cp = ctxp + ((size_t)nh*CTXSPLIT + sp)*CTXSTR;
        s  += cp[p];
        se += cp[512 + k];
    }
    ctx[idx] = s / se;
}

// ---- attended (fused Q-softmax), emits agg in pw1 frag layout ---------------
__global__ __launch_bounds__(256) void attended_kernel(
    const float* __restrict__ ctx, const unsigned short* __restrict__ Qb,
    short* __restrict__ aggf)
{
    const int nh = blockIdx.y;
    const int n = nh >> 3, h = nh & 7;
    const int l = blockIdx.x*256 + threadIdx.x;
    const float* __restrict__ cl = ctx + (size_t)nh*512;

    const unsigned short* Qp = Qb + ((size_t)(n*KCC + h*HK))*LL + l;
    float q[HK];
    float mx = -1e30f;
#pragma unroll
    for (int k = 0; k < HK; ++k) { q[k] = b2f(Qp[(size_t)k*LL]); mx = fmaxf(mx, q[k]); }
    float s = 0.f;
#pragma unroll
    for (int k = 0; k < HK; ++k) { q[k] = __expf(q[k] - mx); s += q[k]; }
    const float inv = 1.f / s;
#pragma unroll
    for (int k = 0; k < HK; ++k) q[k] *= inv;

    float av[HV];
#pragma unroll 4
    for (int v = 0; v < HV; ++v) {
        float acc = 0.f;
#pragma unroll
        for (int k = 0; k < HK; ++k) acc += q[k] * cl[k*HV + v];
        av[v] = acc;
    }
    short* ob = aggf + (size_t)n*XTF_N_STRIDE + ((size_t)((l >> 4)*8 + h))*512;
#pragma unroll
    for (int qd = 0; qd < 4; ++qd) {
        bf16x8 vv;
#pragma unroll
        for (int j = 0; j < 8; ++j) vv[j] = (short)f2b(av[qd*8 + j]);
        *reinterpret_cast<bf16x8*>(ob + (qd*16 + (l & 15))*8) = vv;
    }
}

// ---- pw2r MFMA: reproj + residual -> x bf16, + LN partials ------------------
__global__ __launch_bounds__(256) void pw2r_g(
    const unsigned short* __restrict__ d, const short* __restrict__ w2f,
    const float* __restrict__ bias, const float* __restrict__ resid,
    unsigned short* __restrict__ xout, float* __restrict__ part)
{
    const int z = blockIdx.z, n = blockIdx.y, bx = blockIdx.x;
    const int t = threadIdx.x, wid = t >> 6, lane = t & 63;
    const int mtile = z*4 + wid;
    bf16x8 afr = *reinterpret_cast<const bf16x8*>(
        w2f + ((size_t)(32 + mtile)*512 + lane*8));
    const unsigned short* db = d + (size_t)n*MIDC*LL;
    const int colb = lane & 15, c0 = 8*(lane >> 4);

    f32x4 acc[4];
#pragma unroll
    for (int i = 0; i < 4; ++i) {
#pragma unroll
        for (int r = 0; r < 4; ++r) acc[i][r] = 0.f;
        const unsigned short* p = db + (size_t)c0*LL + (bx*4 + i)*16 + colb;
        bf16x8 bfr;
#pragma unroll
        for (int j = 0; j < 8; ++j) bfr[j] = (short)p[(size_t)j*LL];
        acc[i] = __builtin_amdgcn_mfma_f32_16x16x32_bf16(afr, bfr, acc[i], 0, 0, 0);
    }
    const int m0 = 16*mtile + (lane >> 4)*4;
    float s1 = 0.f, s2 = 0.f;
#pragma unroll
    for (int r = 0; r < 4; ++r) {
        const float bv = bias[m0 + r];
#pragma unroll
        for (int i = 0; i < 4; ++i) {
            const size_t off = (size_t)(n*CIN + m0 + r)*LL + (bx*4 + i)*16 + colb;
            const float v = acc[i][r] + bv + resid[off];
            xout[off] = f2b(v);
            s1 += v; s2 += v*v;
        }
    }
    __shared__ float red[256];
    const int bid = (z*NB + n)*196 + bx;          // < 3136
    red[t] = s1; __syncthreads();
    for (int s = 128; s > 0; s >>= 1) { if (t < s) red[t] += red[t+s]; __syncthreads(); }
    if (t == 0) part[2*bid] = red[0];
    __syncthreads();
    red[t] = s2; __syncthreads();
    for (int s = 128; s > 0; s >>= 1) { if (t < s) red[t] += red[t+s]; __syncthreads(); }
    if (t == 0) part[2*bid + 1] = red[0];
}

__global__ void stats_kernel(const float* __restrict__ part, int nblocks,
                             float* __restrict__ stats)
{
    __shared__ float r1[256], r2[256];
    const int t = threadIdx.x;
    float s1 = 0.f, s2 = 0.f;
    for (int i = t; i < nblocks; i += 256) { s1 += part[2*i]; s2 += part[2*i+1]; }
    r1[t] = s1; r2[t] = s2; __syncthreads();
    for (int s = 128; s > 0; s >>= 1) { if (t < s) { r1[t] += r1[t+s]; r2[t] += r2[t+s]; } __syncthreads(); }
    if (t == 0) {
        const float M = (float)NB*CIN*LL;
        const float mu = r1[0]/M;
        const float var = r2[0]/M - mu*mu;
        stats[0] = mu;
        stats[1] = 1.0f/sqrtf(var + EPSV);
    }
}

__global__ __launch_bounds__(256) void norm_bf16(
    const unsigned short* __restrict__ x, const float* __restrict__ stats,
    float* __restrict__ out)
{
    const float mu = stats[0], inv = stats[1];
    const size_t total = (size_t)NB*CIN*LL;       // divisible by 8
    for (size_t i = ((size_t)blockIdx.x*256 + threadIdx.x)*8; i < total;
         i += (size_t)gridDim.x*256*8) {
        u16x8 v = *reinterpret_cast<const u16x8*>(x + i);
        float4 o0, o1;
        o0.x = (b2f(v[0])-mu)*inv; o0.y = (b2f(v[1])-mu)*inv;
        o0.z = (b2f(v[2])-mu)*inv; o0.w = (b2f(v[3])-mu)*inv;
        o1.x = (b2f(v[4])-mu)*inv; o1.y = (b2f(v[5])-mu)*inv;
        o1.z = (b2f(v[6])-mu)*inv; o1.w = (b2f(v[7])-mu)*inv;
        *reinterpret_cast<float4*>(out + i)     = o0;
        *reinterpret_cast<float4*>(out + i + 4) = o1;
    }
}

// ------------------------------- launcher ------------------------------------
extern "C" void kernel_launch(void* const* d_in, const int* in_sizes, int n_in,
                              void* d_out, int out_size, void* d_ws, size_t ws_size,
                              hipStream_t stream) {
    const float* input   = (const float*)d_in[0];
    const float* k_pw1_w = (const float*)d_in[1];
    const float* k_pw1_b = (const float*)d_in[2];
    const float* k_dw_w  = (const float*)d_in[3];
    const float* k_dw_b  = (const float*)d_in[4];
    const float* k_pw2_w = (const float*)d_in[5];
    const float* k_pw2_b = (const float*)d_in[6];
    const float* q_pw1_w = (const float*)d_in[7];
    const float* q_pw1_b = (const float*)d_in[8];
    const float* q_dw_w  = (const float*)d_in[9];
    const float* q_dw_b  = (const float*)d_in[10];
    const float* q_pw2_w = (const float*)d_in[11];
    const float* q_pw2_b = (const float*)d_in[12];
    const float* v_pw1_w = (const float*)d_in[13];
    const float* v_pw1_b = (const float*)d_in[14];
    const float* v_dw_w  = (const float*)d_in[15];
    const float* v_dw_b  = (const float*)d_in[16];
    const float* v_pw2_w = (const float*)d_in[17];
    const float* v_pw2_b = (const float*)d_in[18];
    const float* r_pw1_w = (const float*)d_in[19];
    const float* r_pw1_b = (const float*)d_in[20];
    const float* r_dw_w  = (const float*)d_in[21];
    const float* r_dw_b  = (const float*)d_in[22];
    const float* r_pw2_w = (const float*)d_in[23];
    const float* r_pw2_b = (const float*)d_in[24];

    // ---- workspace carve (bytes) ----
    char* base = (char*)d_ws;
    // R0 (25,690,112 B): xtf -> dbuf(kqv d, 9.6MB) -> aggf (sequential tenants)
    short* xtf  = (short*)base;
    unsigned short* dbuf = (unsigned short*)base;
    short* aggf = (short*)base;
    // R1: mid(kqv bf16, 9.6MB) -> {mid_r, d_r}
    unsigned short* midb  = (unsigned short*)(base + 25690112);
    unsigned short* mid_r = midb;
    unsigned short* d_r   = (unsigned short*)(base + 25690112 + 6422528);
    // R3: K,Q,V bf16 -> x bf16
    unsigned short* Kb = (unsigned short*)(base + 54591488);
    unsigned short* Qb = (unsigned short*)(base + 67436544);
    unsigned short* Vb = (unsigned short*)(base + 80281600);
    unsigned short* xb = (unsigned short*)(base + 54591488);
    // R4 (small)
    char* H = base + 105971712;
    float* ctxp   = (float*)H;                    // 32*14*544*4 = 974,848 B
    float* ctx    = (float*)(H + 974848);         // 65,536 B
    float* part   = (float*)(H + 1040384);        // 25,088 B
    float* statsp = (float*)(H + 1065472);        // 64 B
    short* w1f    = (short*)(H + 1065536);        // 65,536 B
    short* w2f    = (short*)(H + 1131072);        // 49,152 B

    // 1. weight fragment tables
    {
        WconvA a;
        a.w1[0]=k_pw1_w; a.w1[1]=q_pw1_w; a.w1[2]=v_pw1_w; a.w1[3]=r_pw1_w;
        a.w2[0]=k_pw2_w; a.w2[1]=q_pw2_w; a.w2[2]=v_pw2_w; a.w2[3]=r_pw2_w;
        wconv_kernel<<<28, 256, 0, stream>>>(a, w1f, w2f);
    }
    // 2. input -> frag-major bf16 (high-TLP gather: 6272 blocks)
    transp_in<<<dim3(1568, NB), 256, 0, stream>>>(input, xtf);
    // 3. pw1 k/q/v (MFMA, linear frag reads, shared B) -> mid bf16
    {
        Pw1M a;
        a.wt[0]=w1f;        a.wt[1]=w1f+8192;   a.wt[2]=w1f+16384;
        a.b[0]=k_pw1_b;     a.b[1]=q_pw1_b;     a.b[2]=v_pw1_b;
        a.out[0]=midb;      a.out[1]=midb+MID_SET_STRIDE; a.out[2]=midb+2*MID_SET_STRIDE;
        pw1_frag_t<3><<<dim3(98, NB), 256, 0, stream>>>(xtf, a);
    }
    // 4. depthwise k/q/v -> dbuf bf16 (overwrites xtf, now dead)
    {
        DwA a;
        a.in[0]=midb; a.in[1]=midb+MID_SET_STRIDE; a.in[2]=midb+2*MID_SET_STRIDE;
        a.w[0]=k_dw_w; a.w[1]=q_dw_w; a.w[2]=v_dw_w;
        a.b[0]=k_dw_b; a.b[1]=q_dw_b; a.b[2]=v_dw_b;
        a.out[0]=dbuf; a.out[1]=dbuf+MID_SET_STRIDE; a.out[2]=dbuf+2*MID_SET_STRIDE;
        dw_reg<<<dim3(2, NB*MIDC, 3), 256, 0, stream>>>(a);
    }
    // 5. pw2 k/q/v (MFMA, gathers d from L2; 6272 blocks) -> K,Q,V bf16
    {
        Pw2M a;
        a.w2f = w2f; a.d = dbuf;
        a.b[0]=k_pw2_b; a.b[1]=q_pw2_b; a.b[2]=v_pw2_b;
        a.out[0]=Kb; a.out[1]=Qb; a.out[2]=Vb;
        pw2_g<<<dim3(196, NB, 8), 256, 0, stream>>>(a);
    }
    // 6-7. context (MFMA, no LDS staging)
    ctx_mfma<<<dim3(CTXSPLIT, NB*HC), 256, 0, stream>>>(Kb, Vb, ctxp);
    ctx_reduce<<<64, 256, 0, stream>>>(ctxp, ctx);
    // 8. attended -> aggf (frag layout; overwrites dbuf, now dead)
    attended_kernel<<<dim3(49, NB*HC), 256, 0, stream>>>(ctx, Qb, aggf);
    // 9. pw1 r (MFMA, frag B) -> mid_r bf16
    {
        Pw1M a;
        a.wt[0]=w1f+24576; a.wt[1]=a.wt[0]; a.wt[2]=a.wt[0];
        a.b[0]=r_pw1_b;    a.b[1]=a.b[0];   a.b[2]=a.b[0];
        a.out[0]=mid_r;    a.out[1]=a.out[0]; a.out[2]=a.out[0];
        pw1_frag_t<1><<<dim3(98, NB), 256, 0, stream>>>(aggf, a);
    }
    // 10. depthwise r -> d_r bf16
    {
        DwA a;
        a.in[0]=mid_r; a.w[0]=r_dw_w; a.b[0]=r_dw_b; a.out[0]=d_r;
        a.in[1]=a.in[0]; a.w[1]=a.w[0]; a.b[1]=a.b[0]; a.out[1]=a.out[0];
        a.in[2]=a.in[0]; a.w[2]=a.w[0]; a.b[2]=a.b[0]; a.out[2]=a.out[0];
        dw_reg<<<dim3(2, NB*MIDC, 1), 256, 0, stream>>>(a);
    }
    // 11. pw2 r + residual -> x bf16 + LN partials (overwrites K/Q, now dead)
    pw2r_g<<<dim3(196, NB, 4), 256, 0, stream>>>(d_r, w2f, r_pw2_b, input, xb, part);
    // 12-13. global layernorm
    stats_kernel<<<1, 256, 0, stream>>>(part, 3136, statsp);
    norm_bf16<<<2048, 256, 0, stream>>>(xb, statsp, (float*)d_out);
}

// Round 13
// 143.023 us; speedup vs baseline: 1.1192x; 1.1192x over previous
//
#include <hip/hip_runtime.h>
#include <cstddef>

// Problem constants
#define NB   4
#define CIN  256
#define TT   16
#define HH   28
#define WW   28
#define LL   12544           // 16*28*28 = 784*16
#define MIDC 32
#define KCC  128
#define VCC  256
#define HC   8
#define HK   16
#define HV   32
#define CTXSPLIT 14          // 392 chunks = 14 splits * 4 waves * 7 chunks
#define CTXSTR 544
#define EPSV 1e-5f

typedef __attribute__((ext_vector_type(8))) short bf16x8;
typedef __attribute__((ext_vector_type(8))) unsigned short u16x8;
typedef __attribute__((ext_vector_type(4))) float f32x4;
typedef __attribute__((ext_vector_type(4))) unsigned short u16x4;

__device__ __forceinline__ float b2f(unsigned short u) {
    return __builtin_bit_cast(float, ((unsigned int)u) << 16);
}
__device__ __forceinline__ unsigned short f2b(float f) {
    unsigned int u = __builtin_bit_cast(unsigned int, f);
    u += 0x7FFFu + ((u >> 16) & 1u);          // RNE
    return (unsigned short)(u >> 16);
}

// sizes (elements)
#define XTF_N_STRIDE 3211264ull        // 784*8*512 shorts per sample (aggf)
#define MID_SET_STRIDE 1605632ull      // NB*32*12544 elems per set

struct WconvA { const float* w1[4]; const float* w2[4]; };
struct Pw1M  { const short* wt[3]; const float* b[3]; unsigned short* out[3]; };
struct DwA   { const unsigned short* in[3]; const float* w[3]; const float* b[3]; unsigned short* out[3]; };
struct Pw2M  { const short* w2f; const unsigned short* d; const float* b[3]; unsigned short* out[3]; };

// ---- weights -> fragment-major bf16 tables --------------------------------
__global__ __launch_bounds__(256) void wconv_kernel(WconvA a, short* __restrict__ w1f,
                                                    short* __restrict__ w2f)
{
    const int g = blockIdx.x*256 + threadIdx.x;
    if (g < 4096) {
        const int L = g & 63, kap = (g >> 6) & 7, mt = (g >> 9) & 1, set = g >> 10;
        const int m = 16*mt + (L & 15);
        const int c0 = 32*kap + 8*(L >> 4);
        const float* wp = a.w1[set] + m*CIN + c0;
#pragma unroll
        for (int j = 0; j < 8; ++j) w1f[(size_t)g*8 + j] = (short)f2b(wp[j]);
    } else if (g < 4096 + 3072) {
        const int g2 = g - 4096;
        const int L = g2 & 63, mtg = g2 >> 6;
        int set, mtl;
        if (mtg < 8)       { set = 0; mtl = mtg; }
        else if (mtg < 16) { set = 1; mtl = mtg - 8; }
        else if (mtg < 32) { set = 2; mtl = mtg - 16; }
        else               { set = 3; mtl = mtg - 32; }
        const int m = 16*mtl + (L & 15);
        const int c0 = 8*(L >> 4);
        const float* wp = a.w2[set] + m*MIDC + c0;
#pragma unroll
        for (int j = 0; j < 8; ++j) w2f[(size_t)g2*8 + j] = (short)f2b(wp[j]);
    }
}

// ---- pw1 direct v2: 1 tau per wave, both mt tiles + 3 sets per B-gather ----
// grid (392, NB), block 128 (2 waves) -> 1568 blocks, ~12 waves/CU.
__global__ __launch_bounds__(128) void pw1_direct2(const float* __restrict__ in, Pw1M a)
{
    const int n = blockIdx.y;
    const int t = threadIdx.x, wid = t >> 6, lane = t & 63;
    const int tau = blockIdx.x*2 + wid;
    const float* ib = in + (size_t)n*CIN*LL;
    const int colb = lane & 15, qq = lane >> 4;

    f32x4 acc[3][2];
#pragma unroll
    for (int s = 0; s < 3; ++s)
#pragma unroll
        for (int mt = 0; mt < 2; ++mt)
#pragma unroll
            for (int r = 0; r < 4; ++r) acc[s][mt][r] = 0.f;

    for (int kap = 0; kap < 8; ++kap) {
        const int c0 = 32*kap + 8*qq;
        const float* p = ib + (size_t)c0*LL + tau*16 + colb;
        bf16x8 bfr;
#pragma unroll
        for (int j = 0; j < 8; ++j) bfr[j] = (short)f2b(p[(size_t)j*LL]);
#pragma unroll
        for (int s = 0; s < 3; ++s) {
#pragma unroll
            for (int mt = 0; mt < 2; ++mt) {
                bf16x8 afr = *reinterpret_cast<const bf16x8*>(
                    a.wt[s] + ((mt*8 + kap)*512 + lane*8));
                acc[s][mt] = __builtin_amdgcn_mfma_f32_16x16x32_bf16(afr, bfr, acc[s][mt], 0, 0, 0);
            }
        }
    }
#pragma unroll
    for (int s = 0; s < 3; ++s) {
        const float* bb = a.b[s];
        unsigned short* op = a.out[s] + (size_t)n*MIDC*LL;
#pragma unroll
        for (int mt = 0; mt < 2; ++mt) {
            const int m0 = mt*16 + qq*4;
#pragma unroll
            for (int r = 0; r < 4; ++r)
                op[(size_t)(m0 + r)*LL + tau*16 + colb] = f2b(acc[s][mt][r] + bb[m0 + r]);
        }
    }
}

// ---- pw1 frag-reading variant (for r-branch; B = aggf already frag-major) --
__global__ __launch_bounds__(256) void pw1_frag(const short* __restrict__ xtf, Pw1M a)
{
    const int n = blockIdx.y, bx = blockIdx.x;
    const int t = threadIdx.x, wid = t >> 6, lane = t & 63;
    const int mt = wid & 1, lh = wid >> 1;
    const int tau0 = bx*8 + lh*4;
    const short* xb = xtf + (size_t)n*XTF_N_STRIDE;

    f32x4 acc[4];
#pragma unroll
    for (int i = 0; i < 4; ++i)
#pragma unroll
        for (int r = 0; r < 4; ++r) acc[i][r] = 0.f;

    for (int kap = 0; kap < 8; ++kap) {
        bf16x8 afr = *reinterpret_cast<const bf16x8*>(a.wt[0] + ((mt*8 + kap)*512 + lane*8));
#pragma unroll
        for (int i = 0; i < 4; ++i) {
            bf16x8 bfr = *reinterpret_cast<const bf16x8*>(
                xb + ((size_t)((tau0 + i)*8 + kap)*512 + lane*8));
            acc[i] = __builtin_amdgcn_mfma_f32_16x16x32_bf16(afr, bfr, acc[i], 0, 0, 0);
        }
    }
    const float* bb = a.b[0];
    unsigned short* op = a.out[0] + (size_t)n*MIDC*LL;
    const int col = lane & 15;
    const int m0 = mt*16 + (lane >> 4)*4;
#pragma unroll
    for (int r = 0; r < 4; ++r) {
        const float bv = bb[m0 + r];
#pragma unroll
        for (int i = 0; i < 4; ++i)
            op[(size_t)(m0 + r)*LL + (tau0 + i)*16 + col] = f2b(acc[i][r] + bv);
    }
}

// ---- depthwise 3x3x3, pad 1: register sliding window over t ----------------
struct Row6 { float v[6]; };

__device__ __forceinline__ Row6 load_row(const unsigned short* base, int zz, int yy, int x0)
{
    Row6 r;
    const bool ok = (zz >= 0) && (zz < TT) && (yy >= 0) && (yy < HH);
    if (ok) {
        const unsigned short* p = base + zz*(HH*WW) + yy*WW + x0;
        u16x4 m4 = *reinterpret_cast<const u16x4*>(p);
        r.v[0] = (x0 > 0)  ? b2f(p[-1]) : 0.f;
        r.v[1] = b2f(m4[0]); r.v[2] = b2f(m4[1]);
        r.v[3] = b2f(m4[2]); r.v[4] = b2f(m4[3]);
        r.v[5] = (x0 < 24) ? b2f(p[4]) : 0.f;
    } else {
#pragma unroll
        for (int i = 0; i < 6; ++i) r.v[i] = 0.f;
    }
    return r;
}

__device__ __forceinline__ void acc9(float& a0, float& a1, float& a2, float& a3,
                                     const Row6* rows, const float* w9)
{
#pragma unroll
    for (int dy = 0; dy < 3; ++dy)
#pragma unroll
        for (int dx = 0; dx < 3; ++dx) {
            const float wv = w9[dy*3 + dx];
            a0 = fmaf(wv, rows[dy].v[0 + dx], a0);
            a1 = fmaf(wv, rows[dy].v[1 + dx], a1);
            a2 = fmaf(wv, rows[dy].v[2 + dx], a2);
            a3 = fmaf(wv, rows[dy].v[3 + dx], a3);
        }
}

__global__ __launch_bounds__(256) void dw_reg(DwA a)
{
    const int tid = threadIdx.x;
    if (tid >= 196) return;                  // 7 x-groups * 28 y
    const int z  = blockIdx.z;
    const int nm = blockIdx.y;               // n*32 + m
    const int m  = nm & (MIDC-1);
    const int t0 = blockIdx.x * 8;           // t-half

    const float* wp = a.w[z] + m*27;
    float wv[27];
#pragma unroll
    for (int i = 0; i < 27; ++i) wv[i] = wp[i];
    const float bias = a.b[z][m];

    const int xg = tid % 7, y = tid / 7;
    const int x0 = xg*4;
    const unsigned short* ip = a.in[z] + (size_t)nm*LL;
    unsigned short* op = a.out[z] + (size_t)nm*LL;

    Row6 win[3][3];
#pragma unroll
    for (int dy = 0; dy < 3; ++dy) {
        win[0][dy] = load_row(ip, t0-1, y+dy-1, x0);
        win[1][dy] = load_row(ip, t0,   y+dy-1, x0);
    }
#pragma unroll
    for (int tt = 0; tt < 8; ++tt) {
        const int p0 = tt % 3, p1 = (tt+1) % 3, p2 = (tt+2) % 3;
        const int znew = t0 + tt + 1;
        win[p2][0] = load_row(ip, znew, y-1, x0);
        win[p2][1] = load_row(ip, znew, y,   x0);
        win[p2][2] = load_row(ip, znew, y+1, x0);

        float a0 = bias, a1 = bias, a2 = bias, a3 = bias;
        acc9(a0, a1, a2, a3, win[p0], wv);
        acc9(a0, a1, a2, a3, win[p1], wv + 9);
        acc9(a0, a1, a2, a3, win[p2], wv + 18);

        u16x4 o4 = { f2b(a0), f2b(a1), f2b(a2), f2b(a3) };
        *reinterpret_cast<u16x4*>(op + (size_t)(t0+tt)*(HH*WW) + y*WW + x0) = o4;
    }
}

// ---- pw2 MFMA (gathers B from d directly): [OCx32]@[32xL]+b -> K/Q/V bf16 --
__global__ __launch_bounds__(256) void pw2_g(Pw2M a)
{
    const int z = blockIdx.z, n = blockIdx.y, bx = blockIdx.x;
    int set, chunk;
    if (z < 2)      { set = 0; chunk = z; }
    else if (z < 4) { set = 1; chunk = z - 2; }
    else            { set = 2; chunk = z - 4; }
    const int OC   = (set == 2) ? 256 : 128;
    const int off2 = (set == 0) ? 0 : (set == 1) ? 8 : 16;

    const int t = threadIdx.x, wid = t >> 6, lane = t & 63;
    const int mtile = chunk*4 + wid;
    bf16x8 afr = *reinterpret_cast<const bf16x8*>(
        a.w2f + ((size_t)(off2 + mtile)*512 + lane*8));
    const unsigned short* db = a.d + (size_t)set*MID_SET_STRIDE + (size_t)n*MIDC*LL;
    const int colb = lane & 15, c0 = 8*(lane >> 4);

    f32x4 acc[4];
#pragma unroll
    for (int i = 0; i < 4; ++i) {
#pragma unroll
        for (int r = 0; r < 4; ++r) acc[i][r] = 0.f;
        const unsigned short* p = db + (size_t)c0*LL + (bx*4 + i)*16 + colb;
        bf16x8 bfr;
#pragma unroll
        for (int j = 0; j < 8; ++j) bfr[j] = (short)p[(size_t)j*LL];
        acc[i] = __builtin_amdgcn_mfma_f32_16x16x32_bf16(afr, bfr, acc[i], 0, 0, 0);
    }
    const float* bb = a.b[set];
    unsigned short* op = a.out[set] + (size_t)n*OC*LL;
    const int m0 = 16*mtile + (lane >> 4)*4;
#pragma unroll
    for (int r = 0; r < 4; ++r) {
        const float bv = bb[m0 + r];
#pragma unroll
        for (int i = 0; i < 4; ++i)
            op[(size_t)(m0 + r)*LL + (bx*4 + i)*16 + colb] = f2b(acc[i][r] + bv);
    }
}

// ---- context via MFMA: ctx_partial[k][v] = sum_l exp(K[k,l]) V[v,l] ---------
__global__ __launch_bounds__(256) void ctx_mfma(
    const unsigned short* __restrict__ Kb, const unsigned short* __restrict__ Vb,
    float* __restrict__ ctxp)
{
    const int nh = blockIdx.y;               // 32
    const int sp = blockIdx.x;               // 14
    const int n = nh >> 3, h = nh & 7;
    const int t = threadIdx.x, w = t >> 6, lane = t & 63;
    const int i = lane & 15, q = lane >> 4;

    const unsigned short* Kp = Kb + ((size_t)(n*KCC + h*HK))*LL;
    const unsigned short* Vp = Vb + ((size_t)(n*VCC + h*HV))*LL;

    f32x4 a0 = {0.f,0.f,0.f,0.f}, a1 = {0.f,0.f,0.f,0.f};
    float asum = 0.f;

    const int cbase = sp*28 + w*7;           // 7 chunks of 32 l per wave
#pragma unroll 2
    for (int cc = 0; cc < 7; ++cc) {
        const int l0 = (cbase + cc)*32 + 8*q;
        bf16x8 kf = *reinterpret_cast<const bf16x8*>(Kp + (size_t)i*LL + l0);
        bf16x8 pf;
#pragma unroll
        for (int j = 0; j < 8; ++j) {
            const float e = __expf(b2f((unsigned short)kf[j]));
            asum += e;
            pf[j] = (short)f2b(e);
        }
        bf16x8 b0 = *reinterpret_cast<const bf16x8*>(Vp + (size_t)i*LL + l0);
        bf16x8 b1 = *reinterpret_cast<const bf16x8*>(Vp + (size_t)(i+16)*LL + l0);
        a0 = __builtin_amdgcn_mfma_f32_16x16x32_bf16(pf, b0, a0, 0, 0, 0);
        a1 = __builtin_amdgcn_mfma_f32_16x16x32_bf16(pf, b1, a1, 0, 0, 0);
    }
    asum += __shfl_xor(asum, 16);
    asum += __shfl_xor(asum, 32);

    __shared__ float cs[4][512];
    __shared__ float as[4][16];
#pragma unroll
    for (int r = 0; r < 4; ++r) {
        cs[w][(q*4 + r)*32 + i]      = a0[r];
        cs[w][(q*4 + r)*32 + 16 + i] = a1[r];
    }
    if (q == 0) as[w][i] = asum;
    __syncthreads();
    float* cp = ctxp + ((size_t)nh*CTXSPLIT + sp)*CTXSTR;
    for (int p = t; p < 512; p += 256)
        cp[p] = cs[0][p] + cs[1][p] + cs[2][p] + cs[3][p];
    if (t < 16) cp[512 + t] = as[0][t] + as[1][t] + as[2][t] + as[3][t];
}

__global__ void ctx_reduce(const float* __restrict__ ctxp, float* __restrict__ ctx)
{
    const int idx = blockIdx.x*256 + threadIdx.x;   // 16384
    const int nh = idx >> 9;
    const int p  = idx & 511;
    const int k  = p >> 5;
    float s = 0.f, se = 0.f;
    for (int sp = 0; sp < CTXSPLIT; ++sp) {
        const float* cp = ctxp + ((size_t)nh*CTXSPLIT + sp)*CTXSTR;
        s  += cp[p];
        se += cp[512 + k];
    }
    ctx[idx] = s / se;
}

// ---- attended (fused Q-softmax), emits agg in pw1 frag layout ---------------
__global__ __launch_bounds__(256) void attended_kernel(
    const float* __restrict__ ctx, const unsigned short* __restrict__ Qb,
    short* __restrict__ aggf)
{
    const int nh = blockIdx.y;
    const int n = nh >> 3, h = nh & 7;
    const int l = blockIdx.x*256 + threadIdx.x;
    const float* __restrict__ cl = ctx + (size_t)nh*512;

    const unsigned short* Qp = Qb + ((size_t)(n*KCC + h*HK))*LL + l;
    float q[HK];
    float mx = -1e30f;
#pragma unroll
    for (int k = 0; k < HK; ++k) { q[k] = b2f(Qp[(size_t)k*LL]); mx = fmaxf(mx, q[k]); }
    float s = 0.f;
#pragma unroll
    for (int k = 0; k < HK; ++k) { q[k] = __expf(q[k] - mx); s += q[k]; }
    const float inv = 1.f / s;
#pragma unroll
    for (int k = 0; k < HK; ++k) q[k] *= inv;

    float av[HV];
#pragma unroll 4
    for (int v = 0; v < HV; ++v) {
        float acc = 0.f;
#pragma unroll
        for (int k = 0; k < HK; ++k) acc += q[k] * cl[k*HV + v];
        av[v] = acc;
    }
    short* ob = aggf + (size_t)n*XTF_N_STRIDE + ((size_t)((l >> 4)*8 + h))*512;
#pragma unroll
    for (int qd = 0; qd < 4; ++qd) {
        bf16x8 vv;
#pragma unroll
        for (int j = 0; j < 8; ++j) vv[j] = (short)f2b(av[qd*8 + j]);
        *reinterpret_cast<bf16x8*>(ob + (qd*16 + (l & 15))*8) = vv;
    }
}

// ---- pw2r MFMA: reproj + residual -> x bf16, + LN partials ------------------
__global__ __launch_bounds__(256) void pw2r_g(
    const unsigned short* __restrict__ d, const short* __restrict__ w2f,
    const float* __restrict__ bias, const float* __restrict__ resid,
    unsigned short* __restrict__ xout, float* __restrict__ part)
{
    const int z = blockIdx.z, n = blockIdx.y, bx = blockIdx.x;
    const int t = threadIdx.x, wid = t >> 6, lane = t & 63;
    const int mtile = z*4 + wid;
    bf16x8 afr = *reinterpret_cast<const bf16x8*>(
        w2f + ((size_t)(32 + mtile)*512 + lane*8));
    const unsigned short* db = d + (size_t)n*MIDC*LL;
    const int colb = lane & 15, c0 = 8*(lane >> 4);

    f32x4 acc[4];
#pragma unroll
    for (int i = 0; i < 4; ++i) {
#pragma unroll
        for (int r = 0; r < 4; ++r) acc[i][r] = 0.f;
        const unsigned short* p = db + (size_t)c0*LL + (bx*4 + i)*16 + colb;
        bf16x8 bfr;
#pragma unroll
        for (int j = 0; j < 8; ++j) bfr[j] = (short)p[(size_t)j*LL];
        acc[i] = __builtin_amdgcn_mfma_f32_16x16x32_bf16(afr, bfr, acc[i], 0, 0, 0);
    }
    const int m0 = 16*mtile + (lane >> 4)*4;
    float s1 = 0.f, s2 = 0.f;
#pragma unroll
    for (int r = 0; r < 4; ++r) {
        const float bv = bias[m0 + r];
#pragma unroll
        for (int i = 0; i < 4; ++i) {
            const size_t off = (size_t)(n*CIN + m0 + r)*LL + (bx*4 + i)*16 + colb;
            const float v = acc[i][r] + bv + resid[off];
            xout[off] = f2b(v);
            s1 += v; s2 += v*v;
        }
    }
    __shared__ float red[256];
    const int bid = (z*NB + n)*196 + bx;          // < 3136
    red[t] = s1; __syncthreads();
    for (int s = 128; s > 0; s >>= 1) { if (t < s) red[t] += red[t+s]; __syncthreads(); }
    if (t == 0) part[2*bid] = red[0];
    __syncthreads();
    red[t] = s2; __syncthreads();
    for (int s = 128; s > 0; s >>= 1) { if (t < s) red[t] += red[t+s]; __syncthreads(); }
    if (t == 0) part[2*bid + 1] = red[0];
}

__global__ void stats_kernel(const float* __restrict__ part, int nblocks,
                             float* __restrict__ stats)
{
    __shared__ float r1[256], r2[256];
    const int t = threadIdx.x;
    float s1 = 0.f, s2 = 0.f;
    for (int i = t; i < nblocks; i += 256) { s1 += part[2*i]; s2 += part[2*i+1]; }
    r1[t] = s1; r2[t] = s2; __syncthreads();
    for (int s = 128; s > 0; s >>= 1) { if (t < s) { r1[t] += r1[t+s]; r2[t] += r2[t+s]; } __syncthreads(); }
    if (t == 0) {
        const float M = (float)NB*CIN*LL;
        const float mu = r1[0]/M;
        const float var = r2[0]/M - mu*mu;
        stats[0] = mu;
        stats[1] = 1.0f/sqrtf(var + EPSV);
    }
}

__global__ __launch_bounds__(256) void norm_bf16(
    const unsigned short* __restrict__ x, const float* __restrict__ stats,
    float* __restrict__ out)
{
    const float mu = stats[0], inv = stats[1];
    const size_t total = (size_t)NB*CIN*LL;       // divisible by 8
    for (size_t i = ((size_t)blockIdx.x*256 + threadIdx.x)*8; i < total;
         i += (size_t)gridDim.x*256*8) {
        u16x8 v = *reinterpret_cast<const u16x8*>(x + i);
        float4 o0, o1;
        o0.x = (b2f(v[0])-mu)*inv; o0.y = (b2f(v[1])-mu)*inv;
        o0.z = (b2f(v[2])-mu)*inv; o0.w = (b2f(v[3])-mu)*inv;
        o1.x = (b2f(v[4])-mu)*inv; o1.y = (b2f(v[5])-mu)*inv;
        o1.z = (b2f(v[6])-mu)*inv; o1.w = (b2f(v[7])-mu)*inv;
        *reinterpret_cast<float4*>(out + i)     = o0;
        *reinterpret_cast<float4*>(out + i + 4) = o1;
    }
}

// ------------------------------- launcher ------------------------------------
extern "C" void kernel_launch(void* const* d_in, const int* in_sizes, int n_in,
                              void* d_out, int out_size, void* d_ws, size_t ws_size,
                              hipStream_t stream) {
    const float* input   = (const float*)d_in[0];
    const float* k_pw1_w = (const float*)d_in[1];
    const float* k_pw1_b = (const float*)d_in[2];
    const float* k_dw_w  = (const float*)d_in[3];
    const float* k_dw_b  = (const float*)d_in[4];
    const float* k_pw2_w = (const float*)d_in[5];
    const float* k_pw2_b = (const float*)d_in[6];
    const float* q_pw1_w = (const float*)d_in[7];
    const float* q_pw1_b = (const float*)d_in[8];
    const float* q_dw_w  = (const float*)d_in[9];
    const float* q_dw_b  = (const float*)d_in[10];
    const float* q_pw2_w = (const float*)d_in[11];
    const float* q_pw2_b = (const float*)d_in[12];
    const float* v_pw1_w = (const float*)d_in[13];
    const float* v_pw1_b = (const float*)d_in[14];
    const float* v_dw_w  = (const float*)d_in[15];
    const float* v_dw_b  = (const float*)d_in[16];
    const float* v_pw2_w = (const float*)d_in[17];
    const float* v_pw2_b = (const float*)d_in[18];
    const float* r_pw1_w = (const float*)d_in[19];
    const float* r_pw1_b = (const float*)d_in[20];
    const float* r_dw_w  = (const float*)d_in[21];
    const float* r_dw_b  = (const float*)d_in[22];
    const float* r_pw2_w = (const float*)d_in[23];
    const float* r_pw2_b = (const float*)d_in[24];

    // ---- workspace carve (bytes) ----
    char* base = (char*)d_ws;
    // R0 (25,690,112 B): dbuf(kqv d, 9.6MB) then aggf (25.7MB)
    unsigned short* dbuf = (unsigned short*)base;
    short* aggf = (short*)base;
    // R1: mid(kqv bf16, 9.6MB) -> {mid_r, d_r}
    unsigned short* midb  = (unsigned short*)(base + 25690112);
    unsigned short* mid_r = midb;
    unsigned short* d_r   = (unsigned short*)(base + 25690112 + 6422528);
    // R3: K,Q,V bf16 -> x bf16
    unsigned short* Kb = (unsigned short*)(base + 54591488);
    unsigned short* Qb = (unsigned short*)(base + 67436544);
    unsigned short* Vb = (unsigned short*)(base + 80281600);
    unsigned short* xb = (unsigned short*)(base + 54591488);
    // R4 (small)
    char* H = base + 105971712;
    float* ctxp   = (float*)H;                    // 32*14*544*4 = 974,848 B
    float* ctx    = (float*)(H + 974848);         // 65,536 B
    float* part   = (float*)(H + 1040384);        // 25,088 B
    float* statsp = (float*)(H + 1065472);        // 64 B
    short* w1f    = (short*)(H + 1065536);        // 65,536 B
    short* w2f    = (short*)(H + 1131072);        // 49,152 B

    // 1. weight fragment tables
    {
        WconvA a;
        a.w1[0]=k_pw1_w; a.w1[1]=q_pw1_w; a.w1[2]=v_pw1_w; a.w1[3]=r_pw1_w;
        a.w2[0]=k_pw2_w; a.w2[1]=q_pw2_w; a.w2[2]=v_pw2_w; a.w2[3]=r_pw2_w;
        wconv_kernel<<<28, 256, 0, stream>>>(a, w1f, w2f);
    }
    // 2. pw1 k/q/v (MFMA, direct gather, 1 tau/wave, both mt) -> mid bf16
    {
        Pw1M a;
        a.wt[0]=w1f;        a.wt[1]=w1f+8192;   a.wt[2]=w1f+16384;
        a.b[0]=k_pw1_b;     a.b[1]=q_pw1_b;     a.b[2]=v_pw1_b;
        a.out[0]=midb;      a.out[1]=midb+MID_SET_STRIDE; a.out[2]=midb+2*MID_SET_STRIDE;
        pw1_direct2<<<dim3(392, NB), 128, 0, stream>>>(input, a);
    }
    // 3. depthwise k/q/v -> dbuf bf16
    {
        DwA a;
        a.in[0]=midb; a.in[1]=midb+MID_SET_STRIDE; a.in[2]=midb+2*MID_SET_STRIDE;
        a.w[0]=k_dw_w; a.w[1]=q_dw_w; a.w[2]=v_dw_w;
        a.b[0]=k_dw_b; a.b[1]=q_dw_b; a.b[2]=v_dw_b;
        a.out[0]=dbuf; a.out[1]=dbuf+MID_SET_STRIDE; a.out[2]=dbuf+2*MID_SET_STRIDE;
        dw_reg<<<dim3(2, NB*MIDC, 3), 256, 0, stream>>>(a);
    }
    // 4. pw2 k/q/v (MFMA, gathers d from L2) -> K,Q,V bf16
    {
        Pw2M a;
        a.w2f = w2f; a.d = dbuf;
        a.b[0]=k_pw2_b; a.b[1]=q_pw2_b; a.b[2]=v_pw2_b;
        a.out[0]=Kb; a.out[1]=Qb; a.out[2]=Vb;
        pw2_g<<<dim3(196, NB, 8), 256, 0, stream>>>(a);
    }
    // 5-6. context (MFMA, no LDS staging)
    ctx_mfma<<<dim3(CTXSPLIT, NB*HC), 256, 0, stream>>>(Kb, Vb, ctxp);
    ctx_reduce<<<64, 256, 0, stream>>>(ctxp, ctx);
    // 7. attended -> aggf (frag layout; overwrites dbuf, now dead)
    attended_kernel<<<dim3(49, NB*HC), 256, 0, stream>>>(ctx, Qb, aggf);
    // 8. pw1 r (MFMA, frag B) -> mid_r bf16
    {
        Pw1M a;
        a.wt[0]=w1f+24576; a.wt[1]=a.wt[0]; a.wt[2]=a.wt[0];
        a.b[0]=r_pw1_b;    a.b[1]=a.b[0];   a.b[2]=a.b[0];
        a.out[0]=mid_r;    a.out[1]=a.out[0]; a.out[2]=a.out[0];
        pw1_frag<<<dim3(98, NB), 256, 0, stream>>>(aggf, a);
    }
    // 9. depthwise r -> d_r bf16
    {
        DwA a;
        a.in[0]=mid_r; a.w[0]=r_dw_w; a.b[0]=r_dw_b; a.out[0]=d_r;
        a.in[1]=a.in[0]; a.w[1]=a.w[0]; a.b[1]=a.b[0]; a.out[1]=a.out[0];
        a.in[2]=a.in[0]; a.w[2]=a.w[0]; a.b[2]=a.b[0]; a.out[2]=a.out[0];
        dw_reg<<<dim3(2, NB*MIDC, 1), 256, 0, stream>>>(a);
    }
    // 10. pw2 r + residual -> x bf16 + LN partials (overwrites K/Q, now dead)
    pw2r_g<<<dim3(196, NB, 4), 256, 0, stream>>>(d_r, w2f, r_pw2_b, input, xb, part);
    // 11-12. global layernorm
    stats_kernel<<<1, 256, 0, stream>>>(part, 3136, statsp);
    norm_bf16<<<2048, 256, 0, stream>>>(xb, statsp, (float*)d_out);
}